// Round 1
// baseline (1880.026 us; speedup 1.0000x reference)
//
#include <hip/hip_runtime.h>
#include <math.h>

#define BB 4
#define SS 4096
#define DD 1024
#define DVV 1024
#define CHUNK 128
#define NCHUNK (SS/CHUNK)   // 32

// ---------------- prefix-mean over S (3-phase chunked scan) ----------------

// thread <-> (b, c, d); 131072 threads
__global__ void chunk_sum_k(const float* __restrict__ X, float* __restrict__ csum) {
    int g = blockIdx.x * 256 + threadIdx.x;
    int d = g & (DD - 1);
    int c = (g >> 10) & (NCHUNK - 1);
    int b = g >> 15;
    const float* p = X + ((size_t)(b * SS + c * CHUNK)) * DD + d;
    float s = 0.f;
    for (int t = 0; t < CHUNK; ++t) s += p[(size_t)t * DD];
    csum[g] = s;
}

// thread <-> (b, d); 4096 threads; in-place exclusive prefix over c
__global__ void chunk_prefix_k(float* csum) {
    int g = blockIdx.x * 256 + threadIdx.x;
    int d = g & (DD - 1);
    int b = g >> 10;
    float* p = csum + ((size_t)b * NCHUNK) * DD + d;
    float run = 0.f;
    for (int c = 0; c < NCHUNK; ++c) {
        float v = p[(size_t)c * DD];
        p[(size_t)c * DD] = run;
        run += v;
    }
}

// thread <-> (b, c, d); writes M[b,s,d] = (1/(s+1)) * prefix_sum
__global__ void write_mean_k(const float* __restrict__ X, const float* __restrict__ csum,
                             float* __restrict__ Mout) {
    int g = blockIdx.x * 256 + threadIdx.x;
    int d = g & (DD - 1);
    int c = (g >> 10) & (NCHUNK - 1);
    int b = g >> 15;
    float run = csum[g];
    const float* p = X + ((size_t)(b * SS + c * CHUNK)) * DD + d;
    float* q = Mout + ((size_t)(b * SS + c * CHUNK)) * DD + d;
    int s0 = c * CHUNK;
    for (int t = 0; t < CHUNK; ++t) {
        run += p[(size_t)t * DD];
        q[(size_t)t * DD] = run / (float)(s0 + t + 1);
    }
}

// ---------------- 64x64 fp32 tiled GEMM core ----------------
// As stored [k][m] with pad 68 (16B-aligned float4 rows), Bs [k][n].

__device__ __forceinline__ void gemm_tile_acc(const float* __restrict__ A, int lda,
                                              const float* __restrict__ Bm, int ldb,
                                              int K, int brow, int bcol,
                                              float (*As)[68], float (*Bs)[64],
                                              float acc[4][4]) {
    int tid = threadIdx.x;
    int tx = tid & 15, ty = tid >> 4;
    for (int kt = 0; kt < K; kt += 16) {
        #pragma unroll
        for (int i = 0; i < 4; ++i) {
            int lin = tid + i * 256;
            int k = lin & 15, m = lin >> 4;
            As[k][m] = A[(size_t)(brow * 64 + m) * lda + kt + k];
        }
        #pragma unroll
        for (int i = 0; i < 4; ++i) {
            int lin = tid + i * 256;
            int n = lin & 63, k = lin >> 6;
            Bs[k][n] = Bm[(size_t)(kt + k) * ldb + bcol * 64 + n];
        }
        __syncthreads();
        #pragma unroll
        for (int kk = 0; kk < 16; ++kk) {
            float4 av = *(const float4*)&As[kk][ty * 4];
            float4 bv = *(const float4*)&Bs[kk][tx * 4];
            float a0 = av.x, a1 = av.y, a2 = av.z, a3 = av.w;
            float b0 = bv.x, b1 = bv.y, b2 = bv.z, b3 = bv.w;
            acc[0][0] += a0 * b0; acc[0][1] += a0 * b1; acc[0][2] += a0 * b2; acc[0][3] += a0 * b3;
            acc[1][0] += a1 * b0; acc[1][1] += a1 * b1; acc[1][2] += a1 * b2; acc[1][3] += a1 * b3;
            acc[2][0] += a2 * b0; acc[2][1] += a2 * b1; acc[2][2] += a2 * b2; acc[2][3] += a2 * b3;
            acc[3][0] += a3 * b0; acc[3][1] += a3 * b1; acc[3][2] += a3 * b2; acc[3][3] += a3 * b3;
        }
        __syncthreads();
    }
}

// C = A(M x K) @ B(K x N), row-major, all dims multiples of 64/16
__global__ __launch_bounds__(256) void gemm_plain_k(const float* __restrict__ A,
                                                    const float* __restrict__ Bm,
                                                    float* __restrict__ C, int K, int N) {
    __shared__ float As[16][68];
    __shared__ float Bs[16][64];
    float acc[4][4] = {};
    int brow = blockIdx.x, bcol = blockIdx.y;
    gemm_tile_acc(A, K, Bm, N, K, brow, bcol, As, Bs, acc);
    int tx = threadIdx.x & 15, ty = threadIdx.x >> 4;
    #pragma unroll
    for (int i = 0; i < 4; ++i) {
        int row = brow * 64 + ty * 4 + i;
        float4 o = make_float4(acc[i][0], acc[i][1], acc[i][2], acc[i][3]);
        *(float4*)&C[(size_t)row * N + bcol * 64 + tx * 4] = o;
    }
}

// bias2[b,j] = sum_dv vector[b,dv]*ff1_bot[dv,j] + ff1_bias[j]
__global__ void bias2_k(const float* __restrict__ vec, const float* __restrict__ ff1,
                        const float* __restrict__ ff1b, float* __restrict__ bias2) {
    int g = blockIdx.x * 256 + threadIdx.x;  // 4096
    int j = g & (DD - 1);
    int b = g >> 10;
    const float* fb = ff1 + (size_t)DD * DD;  // ff1_bot
    float s = ff1b[j];
    for (int dv = 0; dv < DVV; ++dv) s += vec[b * DVV + dv] * fb[(size_t)dv * DD + j];
    bias2[g] = s;
}

// hidden = relu(X@ff1_top + M@W2 + bias2[b])
__global__ __launch_bounds__(256) void gemm_ff1_k(const float* __restrict__ X,
                                                  const float* __restrict__ W1,
                                                  const float* __restrict__ Mm,
                                                  const float* __restrict__ W2,
                                                  const float* __restrict__ bias2,
                                                  float* __restrict__ Hout) {
    __shared__ float As[16][68];
    __shared__ float Bs[16][64];
    float acc[4][4] = {};
    int brow = blockIdx.x, bcol = blockIdx.y;
    gemm_tile_acc(X, DD, W1, DD, DD, brow, bcol, As, Bs, acc);
    gemm_tile_acc(Mm, DD, W2, DD, DD, brow, bcol, As, Bs, acc);
    int tx = threadIdx.x & 15, ty = threadIdx.x >> 4;
    int b = brow >> 6;  // 64 m-blocks per batch (4096/64)
    #pragma unroll
    for (int i = 0; i < 4; ++i) {
        int row = brow * 64 + ty * 4 + i;
        int n0 = bcol * 64 + tx * 4;
        float4 bz = *(const float4*)&bias2[b * DD + n0];
        float4 o;
        o.x = fmaxf(acc[i][0] + bz.x, 0.f);
        o.y = fmaxf(acc[i][1] + bz.y, 0.f);
        o.z = fmaxf(acc[i][2] + bz.z, 0.f);
        o.w = fmaxf(acc[i][3] + bz.w, 0.f);
        *(float4*)&Hout[(size_t)row * DD + n0] = o;
    }
}

// P = hidden@ff2 + ff2_bias + X
__global__ __launch_bounds__(256) void gemm_ff2_k(const float* __restrict__ Hin,
                                                  const float* __restrict__ W,
                                                  const float* __restrict__ bias,
                                                  const float* __restrict__ X,
                                                  float* __restrict__ P) {
    __shared__ float As[16][68];
    __shared__ float Bs[16][64];
    float acc[4][4] = {};
    int brow = blockIdx.x, bcol = blockIdx.y;
    gemm_tile_acc(Hin, DD, W, DD, DD, brow, bcol, As, Bs, acc);
    int tx = threadIdx.x & 15, ty = threadIdx.x >> 4;
    #pragma unroll
    for (int i = 0; i < 4; ++i) {
        int row = brow * 64 + ty * 4 + i;
        int n0 = bcol * 64 + tx * 4;
        float4 bz = *(const float4*)&bias[n0];
        float4 xr = *(const float4*)&X[(size_t)row * DD + n0];
        float4 o;
        o.x = acc[i][0] + bz.x + xr.x;
        o.y = acc[i][1] + bz.y + xr.y;
        o.z = acc[i][2] + bz.z + xr.z;
        o.w = acc[i][3] + bz.w + xr.w;
        *(float4*)&P[(size_t)row * DD + n0] = o;
    }
}

// LayerNorm over last dim (1024), one block (256 thr) per row
__global__ __launch_bounds__(256) void ln_k(const float* __restrict__ P,
                                            const float* __restrict__ gam,
                                            const float* __restrict__ bet,
                                            float* __restrict__ out) {
    __shared__ float sbuf[4];
    int row = blockIdx.x;
    int tid = threadIdx.x;
    float4 x = *(const float4*)&P[(size_t)row * DD + tid * 4];
    float local = x.x + x.y + x.z + x.w;
    #pragma unroll
    for (int o = 32; o > 0; o >>= 1) local += __shfl_down(local, o, 64);
    if ((tid & 63) == 0) sbuf[tid >> 6] = local;
    __syncthreads();
    float mu = (sbuf[0] + sbuf[1] + sbuf[2] + sbuf[3]) * (1.0f / 1024.0f);
    __syncthreads();
    float d0 = x.x - mu, d1 = x.y - mu, d2 = x.z - mu, d3 = x.w - mu;
    float v2 = d0 * d0 + d1 * d1 + d2 * d2 + d3 * d3;
    #pragma unroll
    for (int o = 32; o > 0; o >>= 1) v2 += __shfl_down(v2, o, 64);
    if ((tid & 63) == 0) sbuf[tid >> 6] = v2;
    __syncthreads();
    float var = (sbuf[0] + sbuf[1] + sbuf[2] + sbuf[3]) * (1.0f / 1024.0f);
    float rs = rsqrtf(var + 1e-6f);
    float4 gg = *(const float4*)&gam[tid * 4];
    float4 bb = *(const float4*)&bet[tid * 4];
    float4 o4;
    o4.x = d0 * rs * gg.x + bb.x;
    o4.y = d1 * rs * gg.y + bb.y;
    o4.z = d2 * rs * gg.z + bb.z;
    o4.w = d3 * rs * gg.w + bb.w;
    *(float4*)&out[(size_t)row * DD + tid * 4] = o4;
}

extern "C" void kernel_launch(void* const* d_in, const int* in_sizes, int n_in,
                              void* d_out, int out_size, void* d_ws, size_t ws_size,
                              hipStream_t stream) {
    const float* X      = (const float*)d_in[0];   // (B,S,D)
    const float* vec    = (const float*)d_in[1];   // (B,DV)
    // d_in[2] attention_weights, d_in[3] temperature: numerically dead (eps=1e-30 rounds away in fp32)
    const float* values = (const float*)d_in[4];   // (D,H*K) = (1024,1024)
    const float* oper   = (const float*)d_in[5];   // (1024,1024)
    const float* ff1    = (const float*)d_in[6];   // (2048,1024)
    const float* ff1b   = (const float*)d_in[7];   // (1024)
    const float* ff2    = (const float*)d_in[8];   // (1024,1024)
    const float* ff2b   = (const float*)d_in[9];   // (1024)
    const float* gam    = (const float*)d_in[10];
    const float* bet    = (const float*)d_in[11];
    float* out = (float*)d_out;

    float* ws = (float*)d_ws;
    const size_t BSD = (size_t)BB * SS * DD;       // 16777216
    float* Mbuf  = ws;                             // (B*S, D) prefix-mean; reused as P later
    float* Hbuf  = ws + BSD;                       // (B*S, D) hidden
    float* Wv    = ws + 2 * BSD;                   // (1024,1024)
    float* W2    = Wv + (size_t)DD * DD;           // (1024,1024)
    float* bias2 = W2 + (size_t)DD * DD;           // (B, D)
    float* csum  = bias2 + BB * DD;                // (B, NCHUNK, D)

    // prefix mean
    chunk_sum_k<<<512, 256, 0, stream>>>(X, csum);
    chunk_prefix_k<<<16, 256, 0, stream>>>(csum);
    write_mean_k<<<512, 256, 0, stream>>>(X, csum, Mbuf);

    // precompute Wv = values @ operator ; W2 = Wv @ ff1_bot ; bias2
    gemm_plain_k<<<dim3(16, 16), 256, 0, stream>>>(values, oper, Wv, DD, DD);
    gemm_plain_k<<<dim3(16, 16), 256, 0, stream>>>(Wv, ff1 + (size_t)DD * DD, W2, DD, DD);
    bias2_k<<<16, 256, 0, stream>>>(vec, ff1, ff1b, bias2);

    // hidden = relu(X@ff1_top + M@W2 + bias2)
    gemm_ff1_k<<<dim3(256, 16), 256, 0, stream>>>(X, ff1, Mbuf, W2, bias2, Hbuf);

    // P = hidden@ff2 + ff2_bias + X   (P overwrites Mbuf — M is dead)
    gemm_ff2_k<<<dim3(256, 16), 256, 0, stream>>>(Hbuf, ff2, ff2b, X, Mbuf);

    // LayerNorm
    ln_k<<<BB * SS, 256, 0, stream>>>(Mbuf, gam, bet, out);
}

// Round 2
// 569.151 us; speedup vs baseline: 3.3032x; 3.3032x over previous
//
#include <hip/hip_runtime.h>
#include <math.h>

#define BB 4
#define SS 4096
#define DD 1024
#define DVV 1024
#define CHUNK 128
#define NCHUNK (SS/CHUNK)   // 32

typedef unsigned short u16;
typedef __bf16 bf16x8 __attribute__((ext_vector_type(8)));
typedef float f32x4 __attribute__((ext_vector_type(4)));
#define AS1 __attribute__((address_space(1)))
#define AS3 __attribute__((address_space(3)))

__device__ __forceinline__ u16 f2bf(float f) {
    union { float f; unsigned u; } v; v.f = f;
    unsigned r = (v.u + 0x7fffu + ((v.u >> 16) & 1u)) >> 16;
    return (u16)r;
}

// ---------------- prefix-mean over S (3-phase chunked scan) ----------------

__global__ void chunk_sum_k(const float* __restrict__ X, float* __restrict__ csum) {
    int g = blockIdx.x * 256 + threadIdx.x;
    int d = g & (DD - 1);
    int c = (g >> 10) & (NCHUNK - 1);
    int b = g >> 15;
    const float* p = X + ((size_t)(b * SS + c * CHUNK)) * DD + d;
    float s = 0.f;
    for (int t = 0; t < CHUNK; ++t) s += p[(size_t)t * DD];
    csum[g] = s;
}

__global__ void chunk_prefix_k(float* csum) {
    int g = blockIdx.x * 256 + threadIdx.x;
    int d = g & (DD - 1);
    int b = g >> 10;
    float* p = csum + ((size_t)b * NCHUNK) * DD + d;
    float run = 0.f;
    for (int c = 0; c < NCHUNK; ++c) {
        float v = p[(size_t)c * DD];
        p[(size_t)c * DD] = run;
        run += v;
    }
}

// writes Acat[row, 0:1024]   = bf16(X[row])
//        Acat[row, 1024:2048] = bf16(prefix_mean(X)[row])
__global__ void write_mean_conv_k(const float* __restrict__ X, const float* __restrict__ csum,
                                  u16* __restrict__ Acat) {
    int g = blockIdx.x * 256 + threadIdx.x;
    int d = g & (DD - 1);
    int c = (g >> 10) & (NCHUNK - 1);
    int b = g >> 15;
    float run = csum[g];
    const float* p = X + ((size_t)(b * SS + c * CHUNK)) * DD + d;
    u16* q = Acat + ((size_t)(b * SS + c * CHUNK)) * 2048 + d;
    int s0 = c * CHUNK;
    for (int t = 0; t < CHUNK; ++t) {
        float x = p[(size_t)t * DD];
        run += x;
        q[(size_t)t * 2048] = f2bf(x);
        q[(size_t)t * 2048 + 1024] = f2bf(run / (float)(s0 + t + 1));
    }
}

// ---------------- fp32 tiled GEMM (small precomputes only) ----------------

__device__ __forceinline__ void gemm_tile_acc(const float* __restrict__ A, int lda,
                                              const float* __restrict__ Bm, int ldb,
                                              int K, int brow, int bcol,
                                              float (*As)[68], float (*Bs)[64],
                                              float acc[4][4]) {
    int tid = threadIdx.x;
    int tx = tid & 15, ty = tid >> 4;
    for (int kt = 0; kt < K; kt += 16) {
        #pragma unroll
        for (int i = 0; i < 4; ++i) {
            int lin = tid + i * 256;
            int k = lin & 15, m = lin >> 4;
            As[k][m] = A[(size_t)(brow * 64 + m) * lda + kt + k];
        }
        #pragma unroll
        for (int i = 0; i < 4; ++i) {
            int lin = tid + i * 256;
            int n = lin & 63, k = lin >> 6;
            Bs[k][n] = Bm[(size_t)(kt + k) * ldb + bcol * 64 + n];
        }
        __syncthreads();
        #pragma unroll
        for (int kk = 0; kk < 16; ++kk) {
            float4 av = *(const float4*)&As[kk][ty * 4];
            float4 bv = *(const float4*)&Bs[kk][tx * 4];
            float a0 = av.x, a1 = av.y, a2 = av.z, a3 = av.w;
            float b0 = bv.x, b1 = bv.y, b2 = bv.z, b3 = bv.w;
            acc[0][0] += a0 * b0; acc[0][1] += a0 * b1; acc[0][2] += a0 * b2; acc[0][3] += a0 * b3;
            acc[1][0] += a1 * b0; acc[1][1] += a1 * b1; acc[1][2] += a1 * b2; acc[1][3] += a1 * b3;
            acc[2][0] += a2 * b0; acc[2][1] += a2 * b1; acc[2][2] += a2 * b2; acc[2][3] += a2 * b3;
            acc[3][0] += a3 * b0; acc[3][1] += a3 * b1; acc[3][2] += a3 * b2; acc[3][3] += a3 * b3;
        }
        __syncthreads();
    }
}

__global__ __launch_bounds__(256) void gemm_plain_k(const float* __restrict__ A,
                                                    const float* __restrict__ Bm,
                                                    float* __restrict__ C, int K, int N) {
    __shared__ float As[16][68];
    __shared__ float Bs[16][64];
    float acc[4][4] = {};
    int brow = blockIdx.x, bcol = blockIdx.y;
    gemm_tile_acc(A, K, Bm, N, K, brow, bcol, As, Bs, acc);
    int tx = threadIdx.x & 15, ty = threadIdx.x >> 4;
    #pragma unroll
    for (int i = 0; i < 4; ++i) {
        int row = brow * 64 + ty * 4 + i;
        float4 o = make_float4(acc[i][0], acc[i][1], acc[i][2], acc[i][3]);
        *(float4*)&C[(size_t)row * N + bcol * 64 + tx * 4] = o;
    }
}

// bias2[b,j] = sum_dv vector[b,dv]*ff1_bot[dv,j] + ff1_bias[j]
__global__ void bias2_k(const float* __restrict__ vec, const float* __restrict__ ff1,
                        const float* __restrict__ ff1b, float* __restrict__ bias2) {
    int g = blockIdx.x * 256 + threadIdx.x;  // 4096
    int j = g & (DD - 1);
    int b = g >> 10;
    const float* fb = ff1 + (size_t)DD * DD;
    float s = ff1b[j];
    for (int dv = 0; dv < DVV; ++dv) s += vec[b * DVV + dv] * fb[(size_t)dv * DD + j];
    bias2[g] = s;
}

// ---------------- transpose + bf16 convert: dst[n][koff+k] = bf16(src[k][n]) ----------------
__global__ void transp_conv_k(const float* __restrict__ src, int src_ld,
                              u16* __restrict__ dst, int dst_ld, int koff) {
    __shared__ float t[32][33];
    int k0 = blockIdx.x * 32, n0 = blockIdx.y * 32;
    int tx = threadIdx.x, ty = threadIdx.y;  // (32,8)
    #pragma unroll
    for (int i = 0; i < 32; i += 8)
        t[ty + i][tx] = src[(size_t)(k0 + ty + i) * src_ld + n0 + tx];
    __syncthreads();
    #pragma unroll
    for (int i = 0; i < 32; i += 8)
        dst[(size_t)(n0 + ty + i) * dst_ld + koff + k0 + tx] = f2bf(t[tx][ty + i]);
}

// ---------------- bf16 MFMA GEMM, m97 structure ----------------
// C(128x128/block) = A(M x K,row-major) @ Bt(N x K,row-major)^T
// block = 256 thr = 4 waves; wave quadrant (wave&1 -> m-half, wave>>1 -> n-half);
// 4x4 grid of 16x16x32 MFMA per wave; BK=32; global_load_lds width 16.

__device__ __forceinline__ void mfma_core(const u16* __restrict__ Ag, int lda,
                                          const u16* __restrict__ Btg, int ldb,
                                          int K, int bm, int bn,
                                          u16* Alds, u16* Blds, f32x4 acc[4][4]) {
    const int tid = threadIdx.x;
    const int wave = tid >> 6, lane = tid & 63;
    const int lrow = lane >> 2;          // 0..15
    const int lkb = (lane & 3) * 8;      // k elem offset 0,8,16,24
    const int s0 = wave * 2;             // two 16-row segments per wave
    const u16* ga0 = Ag + (size_t)(bm + s0 * 16 + lrow) * lda + lkb;
    const u16* ga1 = Ag + (size_t)(bm + s0 * 16 + 16 + lrow) * lda + lkb;
    const u16* gb0 = Btg + (size_t)(bn + s0 * 16 + lrow) * ldb + lkb;
    const u16* gb1 = Btg + (size_t)(bn + s0 * 16 + 16 + lrow) * ldb + lkb;
    const int lo0 = s0 * 512;            // u16 units: s*1024 bytes
    const int lo1 = lo0 + 512;
    const int fm = (wave & 1) * 64 + (lane & 15);
    const int fn = (wave >> 1) * 64 + (lane & 15);
    const int fk = (lane >> 4) * 8;
    for (int kt = 0; kt < K; kt += 32) {
        __builtin_amdgcn_global_load_lds((const AS1 void*)(ga0 + kt), (AS3 void*)(Alds + lo0), 16, 0, 0);
        __builtin_amdgcn_global_load_lds((const AS1 void*)(ga1 + kt), (AS3 void*)(Alds + lo1), 16, 0, 0);
        __builtin_amdgcn_global_load_lds((const AS1 void*)(gb0 + kt), (AS3 void*)(Blds + lo0), 16, 0, 0);
        __builtin_amdgcn_global_load_lds((const AS1 void*)(gb1 + kt), (AS3 void*)(Blds + lo1), 16, 0, 0);
        __syncthreads();
        bf16x8 af[4], bfr[4];
        #pragma unroll
        for (int i = 0; i < 4; ++i) af[i] = *(const bf16x8*)&Alds[(fm + i * 16) * 32 + fk];
        #pragma unroll
        for (int i = 0; i < 4; ++i) bfr[i] = *(const bf16x8*)&Blds[(fn + i * 16) * 32 + fk];
        #pragma unroll
        for (int mi = 0; mi < 4; ++mi)
            #pragma unroll
            for (int ni = 0; ni < 4; ++ni)
                acc[mi][ni] = __builtin_amdgcn_mfma_f32_16x16x32_bf16(af[mi], bfr[ni], acc[mi][ni], 0, 0, 0);
        __syncthreads();
    }
}

// hidden = relu(Acat @ Bt1^T + bias2[b]) -> bf16
__global__ __launch_bounds__(256) void mfma_ff1_k(const u16* __restrict__ Acat,
                                                  const u16* __restrict__ Bt1,
                                                  const float* __restrict__ bias2,
                                                  u16* __restrict__ H) {
    __shared__ u16 Alds[128 * 32];
    __shared__ u16 Blds[128 * 32];
    f32x4 acc[4][4] = {};
    int bn = blockIdx.x * 128, bm = blockIdx.y * 128;
    mfma_core(Acat, 2048, Bt1, 2048, 2048, bm, bn, Alds, Blds, acc);
    int wave = threadIdx.x >> 6, lane = threadIdx.x & 63;
    int rbase = bm + (wave & 1) * 64 + (lane >> 4) * 4;
    int cbase = bn + (wave >> 1) * 64 + (lane & 15);
    int bb = bm >> 12;
    #pragma unroll
    for (int mi = 0; mi < 4; ++mi)
        #pragma unroll
        for (int ni = 0; ni < 4; ++ni) {
            int col = cbase + ni * 16;
            float bz = bias2[bb * 1024 + col];
            #pragma unroll
            for (int r = 0; r < 4; ++r) {
                int row = rbase + mi * 16 + r;
                float v = acc[mi][ni][r] + bz;
                H[(size_t)row * 1024 + col] = f2bf(fmaxf(v, 0.f));
            }
        }
}

// P = H @ Bt2^T + ff2_bias + X -> fp32
__global__ __launch_bounds__(256) void mfma_ff2_k(const u16* __restrict__ H,
                                                  const u16* __restrict__ Bt2,
                                                  const float* __restrict__ ff2b,
                                                  const float* __restrict__ X,
                                                  float* __restrict__ P) {
    __shared__ u16 Alds[128 * 32];
    __shared__ u16 Blds[128 * 32];
    f32x4 acc[4][4] = {};
    int bn = blockIdx.x * 128, bm = blockIdx.y * 128;
    mfma_core(H, 1024, Bt2, 1024, 1024, bm, bn, Alds, Blds, acc);
    int wave = threadIdx.x >> 6, lane = threadIdx.x & 63;
    int rbase = bm + (wave & 1) * 64 + (lane >> 4) * 4;
    int cbase = bn + (wave >> 1) * 64 + (lane & 15);
    #pragma unroll
    for (int mi = 0; mi < 4; ++mi)
        #pragma unroll
        for (int ni = 0; ni < 4; ++ni) {
            int col = cbase + ni * 16;
            float bz = ff2b[col];
            #pragma unroll
            for (int r = 0; r < 4; ++r) {
                int row = rbase + mi * 16 + r;
                P[(size_t)row * 1024 + col] = acc[mi][ni][r] + bz + X[(size_t)row * 1024 + col];
            }
        }
}

// ---------------- LayerNorm ----------------
__global__ __launch_bounds__(256) void ln_k(const float* __restrict__ P,
                                            const float* __restrict__ gam,
                                            const float* __restrict__ bet,
                                            float* __restrict__ out) {
    __shared__ float sbuf[4];
    int row = blockIdx.x;
    int tid = threadIdx.x;
    float4 x = *(const float4*)&P[(size_t)row * DD + tid * 4];
    float local = x.x + x.y + x.z + x.w;
    #pragma unroll
    for (int o = 32; o > 0; o >>= 1) local += __shfl_down(local, o, 64);
    if ((tid & 63) == 0) sbuf[tid >> 6] = local;
    __syncthreads();
    float mu = (sbuf[0] + sbuf[1] + sbuf[2] + sbuf[3]) * (1.0f / 1024.0f);
    __syncthreads();
    float d0 = x.x - mu, d1 = x.y - mu, d2 = x.z - mu, d3 = x.w - mu;
    float v2 = d0 * d0 + d1 * d1 + d2 * d2 + d3 * d3;
    #pragma unroll
    for (int o = 32; o > 0; o >>= 1) v2 += __shfl_down(v2, o, 64);
    if ((tid & 63) == 0) sbuf[tid >> 6] = v2;
    __syncthreads();
    float var = (sbuf[0] + sbuf[1] + sbuf[2] + sbuf[3]) * (1.0f / 1024.0f);
    float rs = rsqrtf(var + 1e-6f);
    float4 gg = *(const float4*)&gam[tid * 4];
    float4 bb = *(const float4*)&bet[tid * 4];
    float4 o4;
    o4.x = d0 * rs * gg.x + bb.x;
    o4.y = d1 * rs * gg.y + bb.y;
    o4.z = d2 * rs * gg.z + bb.z;
    o4.w = d3 * rs * gg.w + bb.w;
    *(float4*)&out[(size_t)row * DD + tid * 4] = o4;
}

extern "C" void kernel_launch(void* const* d_in, const int* in_sizes, int n_in,
                              void* d_out, int out_size, void* d_ws, size_t ws_size,
                              hipStream_t stream) {
    const float* X      = (const float*)d_in[0];
    const float* vec    = (const float*)d_in[1];
    // d_in[2] attention_weights, d_in[3] temperature: numerically dead (eps=1e-30 rounds away in fp32)
    const float* values = (const float*)d_in[4];
    const float* oper   = (const float*)d_in[5];
    const float* ff1    = (const float*)d_in[6];
    const float* ff1b   = (const float*)d_in[7];
    const float* ff2    = (const float*)d_in[8];
    const float* ff2b   = (const float*)d_in[9];
    const float* gam    = (const float*)d_in[10];
    const float* bet    = (const float*)d_in[11];
    float* out = (float*)d_out;

    char* w = (char*)d_ws;
    u16*   Acat  = (u16*)w;                                 // 16384x2048 bf16 = 64 MB
    float* P     = (float*)w;                               // alias (Acat dead when P written)
    u16*   Hbf   = (u16*)(w + (size_t)(64u << 20));         // 16384x1024 bf16 = 32 MB
    float* Wv    = (float*)(w + (size_t)(96u << 20));       // 4 MB
    float* W2    = (float*)(w + (size_t)(100u << 20));      // 4 MB
    u16*   Bt1   = (u16*)(w + (size_t)(104u << 20));        // 1024x2048 bf16 = 4 MB
    u16*   Bt2   = (u16*)(w + (size_t)(108u << 20));        // 1024x1024 bf16 = 2 MB
    float* bias2 = (float*)(w + (size_t)(110u << 20));      // 16 KB
    float* csum  = (float*)(w + (size_t)(110u << 20) + (1u << 16)); // 512 KB

    // prefix mean + bf16 pack of [X | M]
    chunk_sum_k<<<512, 256, 0, stream>>>(X, csum);
    chunk_prefix_k<<<16, 256, 0, stream>>>(csum);
    write_mean_conv_k<<<512, 256, 0, stream>>>(X, csum, Acat);

    // precompute W2 = (values@operator)@ff1_bot (fp32), bias2
    gemm_plain_k<<<dim3(16, 16), 256, 0, stream>>>(values, oper, Wv, DD, DD);
    gemm_plain_k<<<dim3(16, 16), 256, 0, stream>>>(Wv, ff1 + (size_t)DD * DD, W2, DD, DD);
    bias2_k<<<16, 256, 0, stream>>>(vec, ff1, ff1b, bias2);

    // transposed bf16 weights: Bt1 = [ff1_top; W2]^T, Bt2 = ff2^T
    transp_conv_k<<<dim3(32, 32), dim3(32, 8), 0, stream>>>(ff1, DD, Bt1, 2048, 0);
    transp_conv_k<<<dim3(32, 32), dim3(32, 8), 0, stream>>>(W2, DD, Bt1, 2048, 1024);
    transp_conv_k<<<dim3(32, 32), dim3(32, 8), 0, stream>>>(ff2, DD, Bt2, 1024, 0);

    // hidden = relu([X|M] @ [W1;W2] + bias2)   (K=2048, grid x=N-blocks for L2 reuse)
    mfma_ff1_k<<<dim3(8, 128), 256, 0, stream>>>(Acat, Bt1, bias2, Hbf);

    // P = hidden @ ff2 + ff2b + X
    mfma_ff2_k<<<dim3(8, 128), 256, 0, stream>>>(Hbf, Bt2, ff2b, X, P);

    // LayerNorm
    ln_k<<<BB * SS, 256, 0, stream>>>(P, gam, bet, out);
}

// Round 3
// 396.301 us; speedup vs baseline: 4.7439x; 1.4362x over previous
//
#include <hip/hip_runtime.h>
#include <math.h>

#define BB 4
#define SS 4096
#define DD 1024
#define DVV 1024
#define CHUNK 128
#define NCHUNK (SS/CHUNK)   // 32

typedef unsigned short u16;
typedef __bf16 bf16x8 __attribute__((ext_vector_type(8)));
typedef float f32x4 __attribute__((ext_vector_type(4)));
#define AS1 __attribute__((address_space(1)))
#define AS3 __attribute__((address_space(3)))

__device__ __forceinline__ u16 f2bf(float f) {
    union { float f; unsigned u; } v; v.f = f;
    unsigned r = (v.u + 0x7fffu + ((v.u >> 16) & 1u)) >> 16;
    return (u16)r;
}
__device__ __forceinline__ float bf2f(u16 h) {
    union { unsigned u; float f; } v; v.u = ((unsigned)h) << 16;
    return v.f;
}

// ---------------- prefix-mean over S (3-phase chunked scan) ----------------

__global__ void chunk_sum_k(const float* __restrict__ X, float* __restrict__ csum) {
    int g = blockIdx.x * 256 + threadIdx.x;
    int d = g & (DD - 1);
    int c = (g >> 10) & (NCHUNK - 1);
    int b = g >> 15;
    const float* p = X + ((size_t)(b * SS + c * CHUNK)) * DD + d;
    float s = 0.f;
    for (int t = 0; t < CHUNK; ++t) s += p[(size_t)t * DD];
    csum[g] = s;
}

__global__ void chunk_prefix_k(float* csum) {
    int g = blockIdx.x * 256 + threadIdx.x;
    int d = g & (DD - 1);
    int b = g >> 10;
    float* p = csum + ((size_t)b * NCHUNK) * DD + d;
    float run = 0.f;
    for (int c = 0; c < NCHUNK; ++c) {
        float v = p[(size_t)c * DD];
        p[(size_t)c * DD] = run;
        run += v;
    }
}

// Acat[row,0:1024]=bf16(X[row]); Acat[row,1024:2048]=bf16(prefix_mean[row])
__global__ void write_mean_conv_k(const float* __restrict__ X, const float* __restrict__ csum,
                                  u16* __restrict__ Acat) {
    int g = blockIdx.x * 256 + threadIdx.x;
    int d = g & (DD - 1);
    int c = (g >> 10) & (NCHUNK - 1);
    int b = g >> 15;
    float run = csum[g];
    const float* p = X + ((size_t)(b * SS + c * CHUNK)) * DD + d;
    u16* q = Acat + ((size_t)(b * SS + c * CHUNK)) * 2048 + d;
    int s0 = c * CHUNK;
    for (int t = 0; t < CHUNK; ++t) {
        float x = p[(size_t)t * DD];
        run += x;
        q[(size_t)t * 2048] = f2bf(x);
        q[(size_t)t * 2048 + 1024] = f2bf(run / (float)(s0 + t + 1));
    }
}

// ---------------- small converts / transposes ----------------

// elementwise fp32 -> bf16 (n multiple of 1024)
__global__ void conv_k(const float* __restrict__ src, u16* __restrict__ dst) {
    int g = blockIdx.x * 256 + threadIdx.x;
    float4 v = *(const float4*)&src[(size_t)g * 4];
    u16* o = dst + (size_t)g * 4;
    o[0] = f2bf(v.x); o[1] = f2bf(v.y); o[2] = f2bf(v.z); o[3] = f2bf(v.w);
}

// dst[n][koff+k] = bf16(src[k][n])
__global__ void transp_conv_k(const float* __restrict__ src, int src_ld,
                              u16* __restrict__ dst, int dst_ld, int koff) {
    __shared__ float t[32][33];
    int k0 = blockIdx.x * 32, n0 = blockIdx.y * 32;
    int tx = threadIdx.x, ty = threadIdx.y;  // (32,8)
    #pragma unroll
    for (int i = 0; i < 32; i += 8)
        t[ty + i][tx] = src[(size_t)(k0 + ty + i) * src_ld + n0 + tx];
    __syncthreads();
    #pragma unroll
    for (int i = 0; i < 32; i += 8)
        dst[(size_t)(n0 + ty + i) * dst_ld + koff + k0 + tx] = f2bf(t[tx][ty + i]);
}

// bias2[b,j] = sum_dv vector[b,dv]*ff1_bot[dv,j] + ff1_bias[j]; grid 32 x 256
__global__ __launch_bounds__(256) void bias2_k(const float* __restrict__ vec,
                                               const float* __restrict__ ff1,
                                               const float* __restrict__ ff1b,
                                               float* __restrict__ bias2) {
    __shared__ float red[8][4][32];
    int j0 = blockIdx.x * 32;
    int t = threadIdx.x;
    int j = t & 31, g = t >> 5;
    const float* fb = ff1 + (size_t)DD * DD;
    float s[4] = {0.f, 0.f, 0.f, 0.f};
    for (int dv = g * 128; dv < g * 128 + 128; ++dv) {
        float w = fb[(size_t)dv * DD + j0 + j];
        s[0] += vec[dv] * w;
        s[1] += vec[DVV + dv] * w;
        s[2] += vec[2 * DVV + dv] * w;
        s[3] += vec[3 * DVV + dv] * w;
    }
    #pragma unroll
    for (int b = 0; b < 4; ++b) red[g][b][j] = s[b];
    __syncthreads();
    if (t < 128) {
        int jj = t & 31, b = t >> 5;
        float acc = ff1b[j0 + jj];
        #pragma unroll
        for (int gg = 0; gg < 8; ++gg) acc += red[gg][b][jj];
        bias2[b * DD + j0 + jj] = acc;
    }
}

// ---------------- 64x64 bf16 MFMA GEMM (precomputes): C = A @ Bt^T -> bf16 ----------------
// A (M x K) row-major bf16, Bt (N x K) row-major bf16. grid (N/64, M/64), 256 thr.
__global__ __launch_bounds__(256) void mfma64_k(const u16* __restrict__ Ag,
                                                const u16* __restrict__ Btg,
                                                u16* __restrict__ dst, int K,
                                                int dld, int koff) {
    __shared__ u16 Alds[64 * 32];
    __shared__ u16 Blds[64 * 32];
    f32x4 acc[2][2] = {};
    int bm = blockIdx.y * 64, bn = blockIdx.x * 64;
    const int tid = threadIdx.x;
    const int wave = tid >> 6, lane = tid & 63;
    const int wm = wave & 1, wn = wave >> 1;
    const u16* ga = Ag + (size_t)(bm + (tid >> 2)) * K + (tid & 3) * 8;
    const u16* gb = Btg + (size_t)(bn + (tid >> 2)) * K + (tid & 3) * 8;
    const int lo = tid * 8;
    const int fk = (lane >> 4) * 8;
    for (int kt = 0; kt < K; kt += 32) {
        __builtin_amdgcn_global_load_lds((const AS1 void*)(ga + kt), (AS3 void*)(Alds + lo), 16, 0, 0);
        __builtin_amdgcn_global_load_lds((const AS1 void*)(gb + kt), (AS3 void*)(Blds + lo), 16, 0, 0);
        __syncthreads();
        bf16x8 af[2], bfr[2];
        #pragma unroll
        for (int i = 0; i < 2; ++i) af[i] = *(const bf16x8*)&Alds[(wm * 32 + i * 16 + (lane & 15)) * 32 + fk];
        #pragma unroll
        for (int i = 0; i < 2; ++i) bfr[i] = *(const bf16x8*)&Blds[(wn * 32 + i * 16 + (lane & 15)) * 32 + fk];
        #pragma unroll
        for (int mi = 0; mi < 2; ++mi)
            #pragma unroll
            for (int ni = 0; ni < 2; ++ni)
                acc[mi][ni] = __builtin_amdgcn_mfma_f32_16x16x32_bf16(af[mi], bfr[ni], acc[mi][ni], 0, 0, 0);
        __syncthreads();
    }
    #pragma unroll
    for (int mi = 0; mi < 2; ++mi)
        #pragma unroll
        for (int ni = 0; ni < 2; ++ni) {
            int col = bn + wn * 32 + ni * 16 + (lane & 15);
            #pragma unroll
            for (int r = 0; r < 4; ++r) {
                int row = bm + wm * 32 + mi * 16 + (lane >> 4) * 4 + r;
                dst[(size_t)row * dld + koff + col] = f2bf(acc[mi][ni][r]);
            }
        }
}

// ---------------- 128x128 bf16 MFMA GEMM core (m97 structure) ----------------

__device__ __forceinline__ void mfma_core(const u16* __restrict__ Ag, int lda,
                                          const u16* __restrict__ Btg, int ldb,
                                          int K, int bm, int bn,
                                          u16* Alds, u16* Blds, f32x4 acc[4][4]) {
    const int tid = threadIdx.x;
    const int wave = tid >> 6, lane = tid & 63;
    const int lrow = lane >> 2;
    const int lkb = (lane & 3) * 8;
    const int s0 = wave * 2;
    const u16* ga0 = Ag + (size_t)(bm + s0 * 16 + lrow) * lda + lkb;
    const u16* ga1 = Ag + (size_t)(bm + s0 * 16 + 16 + lrow) * lda + lkb;
    const u16* gb0 = Btg + (size_t)(bn + s0 * 16 + lrow) * ldb + lkb;
    const u16* gb1 = Btg + (size_t)(bn + s0 * 16 + 16 + lrow) * ldb + lkb;
    const int lo0 = s0 * 512;
    const int lo1 = lo0 + 512;
    const int fm = (wave & 1) * 64 + (lane & 15);
    const int fn = (wave >> 1) * 64 + (lane & 15);
    const int fk = (lane >> 4) * 8;
    for (int kt = 0; kt < K; kt += 32) {
        __builtin_amdgcn_global_load_lds((const AS1 void*)(ga0 + kt), (AS3 void*)(Alds + lo0), 16, 0, 0);
        __builtin_amdgcn_global_load_lds((const AS1 void*)(ga1 + kt), (AS3 void*)(Alds + lo1), 16, 0, 0);
        __builtin_amdgcn_global_load_lds((const AS1 void*)(gb0 + kt), (AS3 void*)(Blds + lo0), 16, 0, 0);
        __builtin_amdgcn_global_load_lds((const AS1 void*)(gb1 + kt), (AS3 void*)(Blds + lo1), 16, 0, 0);
        __syncthreads();
        bf16x8 af[4], bfr[4];
        #pragma unroll
        for (int i = 0; i < 4; ++i) af[i] = *(const bf16x8*)&Alds[(fm + i * 16) * 32 + fk];
        #pragma unroll
        for (int i = 0; i < 4; ++i) bfr[i] = *(const bf16x8*)&Blds[(fn + i * 16) * 32 + fk];
        #pragma unroll
        for (int mi = 0; mi < 4; ++mi)
            #pragma unroll
            for (int ni = 0; ni < 4; ++ni)
                acc[mi][ni] = __builtin_amdgcn_mfma_f32_16x16x32_bf16(af[mi], bfr[ni], acc[mi][ni], 0, 0, 0);
        __syncthreads();
    }
}

// XCD-aware remap: blocks sharing an A m-tile land on the same XCD (bid%8).
__device__ __forceinline__ void swizzle_mn(int nblk_n, int& bm, int& bn) {
    int bid = blockIdx.y * nblk_n + blockIdx.x;
    int x = bid & 7;
    int j = bid >> 3;
    int nt = j & (nblk_n - 1);
    int mt = (j >> 3) * 8 + x;   // nblk_n == 8
    bm = mt * 128;
    bn = nt * 128;
}

// hidden = relu(Acat @ Bt1^T + bias2[b]) -> bf16
__global__ __launch_bounds__(256) void mfma_ff1_k(const u16* __restrict__ Acat,
                                                  const u16* __restrict__ Bt1,
                                                  const float* __restrict__ bias2,
                                                  u16* __restrict__ H) {
    __shared__ u16 Alds[128 * 32];
    __shared__ u16 Blds[128 * 32];
    f32x4 acc[4][4] = {};
    int bm, bn;
    swizzle_mn(8, bm, bn);
    mfma_core(Acat, 2048, Bt1, 2048, 2048, bm, bn, Alds, Blds, acc);
    int wave = threadIdx.x >> 6, lane = threadIdx.x & 63;
    int rbase = bm + (wave & 1) * 64 + (lane >> 4) * 4;
    int cbase = bn + (wave >> 1) * 64 + (lane & 15);
    int bb = bm >> 12;
    #pragma unroll
    for (int mi = 0; mi < 4; ++mi)
        #pragma unroll
        for (int ni = 0; ni < 4; ++ni) {
            int col = cbase + ni * 16;
            float bz = bias2[bb * 1024 + col];
            #pragma unroll
            for (int r = 0; r < 4; ++r) {
                int row = rbase + mi * 16 + r;
                float v = acc[mi][ni][r] + bz;
                H[(size_t)row * 1024 + col] = f2bf(fmaxf(v, 0.f));
            }
        }
}

// P = H @ Bt2^T + ff2_bias + X -> bf16
__global__ __launch_bounds__(256) void mfma_ff2_k(const u16* __restrict__ H,
                                                  const u16* __restrict__ Bt2,
                                                  const float* __restrict__ ff2b,
                                                  const float* __restrict__ X,
                                                  u16* __restrict__ P) {
    __shared__ u16 Alds[128 * 32];
    __shared__ u16 Blds[128 * 32];
    f32x4 acc[4][4] = {};
    int bm, bn;
    swizzle_mn(8, bm, bn);
    mfma_core(H, 1024, Bt2, 1024, 1024, bm, bn, Alds, Blds, acc);
    int wave = threadIdx.x >> 6, lane = threadIdx.x & 63;
    int rbase = bm + (wave & 1) * 64 + (lane >> 4) * 4;
    int cbase = bn + (wave >> 1) * 64 + (lane & 15);
    #pragma unroll
    for (int mi = 0; mi < 4; ++mi)
        #pragma unroll
        for (int ni = 0; ni < 4; ++ni) {
            int col = cbase + ni * 16;
            float bz = ff2b[col];
            #pragma unroll
            for (int r = 0; r < 4; ++r) {
                int row = rbase + mi * 16 + r;
                P[(size_t)row * 1024 + col] = f2bf(acc[mi][ni][r] + bz + X[(size_t)row * 1024 + col]);
            }
        }
}

// ---------------- LayerNorm over bf16 P -> fp32 out ----------------
__global__ __launch_bounds__(256) void ln_k(const u16* __restrict__ P,
                                            const float* __restrict__ gam,
                                            const float* __restrict__ bet,
                                            float* __restrict__ out) {
    __shared__ float sbuf[4];
    int row = blockIdx.x;
    int tid = threadIdx.x;
    const u16* pr = P + (size_t)row * DD + tid * 4;
    float x0 = bf2f(pr[0]), x1 = bf2f(pr[1]), x2 = bf2f(pr[2]), x3 = bf2f(pr[3]);
    float local = x0 + x1 + x2 + x3;
    #pragma unroll
    for (int o = 32; o > 0; o >>= 1) local += __shfl_down(local, o, 64);
    if ((tid & 63) == 0) sbuf[tid >> 6] = local;
    __syncthreads();
    float mu = (sbuf[0] + sbuf[1] + sbuf[2] + sbuf[3]) * (1.0f / 1024.0f);
    __syncthreads();
    float d0 = x0 - mu, d1 = x1 - mu, d2 = x2 - mu, d3 = x3 - mu;
    float v2 = d0 * d0 + d1 * d1 + d2 * d2 + d3 * d3;
    #pragma unroll
    for (int o = 32; o > 0; o >>= 1) v2 += __shfl_down(v2, o, 64);
    if ((tid & 63) == 0) sbuf[tid >> 6] = v2;
    __syncthreads();
    float var = (sbuf[0] + sbuf[1] + sbuf[2] + sbuf[3]) * (1.0f / 1024.0f);
    float rs = rsqrtf(var + 1e-6f);
    float4 gg = *(const float4*)&gam[tid * 4];
    float4 bb = *(const float4*)&bet[tid * 4];
    float4 o4;
    o4.x = d0 * rs * gg.x + bb.x;
    o4.y = d1 * rs * gg.y + bb.y;
    o4.z = d2 * rs * gg.z + bb.z;
    o4.w = d3 * rs * gg.w + bb.w;
    *(float4*)&out[(size_t)row * DD + tid * 4] = o4;
}

extern "C" void kernel_launch(void* const* d_in, const int* in_sizes, int n_in,
                              void* d_out, int out_size, void* d_ws, size_t ws_size,
                              hipStream_t stream) {
    const float* X      = (const float*)d_in[0];
    const float* vec    = (const float*)d_in[1];
    // d_in[2] attention_weights, d_in[3] temperature: numerically dead (eps=1e-30 rounds away in fp32)
    const float* values = (const float*)d_in[4];
    const float* oper   = (const float*)d_in[5];
    const float* ff1    = (const float*)d_in[6];
    const float* ff1b   = (const float*)d_in[7];
    const float* ff2    = (const float*)d_in[8];
    const float* ff2b   = (const float*)d_in[9];
    const float* gam    = (const float*)d_in[10];
    const float* bet    = (const float*)d_in[11];
    float* out = (float*)d_out;

    char* w = (char*)d_ws;
    u16*   Acat  = (u16*)w;                                  // 64 MB (16384x2048)
    u16*   Pbf   = (u16*)w;                                  // alias: Acat dead when P written
    u16*   Hbf   = (u16*)(w + (size_t)(64u << 20));          // 32 MB
    u16*   Vbf   = (u16*)(w + (size_t)(96u << 20));          // 2 MB values bf16
    u16*   OpT   = (u16*)(w + (size_t)(98u << 20));          // 2 MB operator^T bf16
    u16*   FbT   = (u16*)(w + (size_t)(100u << 20));         // 2 MB ff1_bot^T bf16
    u16*   WvBf  = (u16*)(w + (size_t)(102u << 20));         // 2 MB Wv bf16
    u16*   Bt1   = (u16*)(w + (size_t)(104u << 20));         // 4 MB (1024x2048)
    u16*   Bt2   = (u16*)(w + (size_t)(108u << 20));         // 2 MB (1024x1024)
    float* bias2 = (float*)(w + (size_t)(110u << 20));       // 16 KB
    float* csum  = (float*)(w + (size_t)(110u << 20) + (1u << 16)); // 512 KB

    // --- tiny precompute chain (bf16 MFMA) ---
    conv_k<<<1024, 256, 0, stream>>>(values, Vbf);
    transp_conv_k<<<dim3(32, 32), dim3(32, 8), 0, stream>>>(oper, DD, OpT, 1024, 0);
    transp_conv_k<<<dim3(32, 32), dim3(32, 8), 0, stream>>>(ff1 + (size_t)DD * DD, DD, FbT, 1024, 0);
    transp_conv_k<<<dim3(32, 32), dim3(32, 8), 0, stream>>>(ff1, DD, Bt1, 2048, 0);
    transp_conv_k<<<dim3(32, 32), dim3(32, 8), 0, stream>>>(ff2, DD, Bt2, 1024, 0);
    // Wv(k,d) = sum_hk values(k,hk)*operT(d,hk)
    mfma64_k<<<dim3(16, 16), 256, 0, stream>>>(Vbf, OpT, WvBf, 1024, 1024, 0);
    // Bt1[n,1024+k] = W2(k,n) = sum_d FbT(n,d)*Wv(k,d)
    mfma64_k<<<dim3(16, 16), 256, 0, stream>>>(FbT, WvBf, Bt1, 1024, 2048, 1024);
    bias2_k<<<32, 256, 0, stream>>>(vec, ff1, ff1b, bias2);

    // --- prefix mean + bf16 pack of [X | M] ---
    chunk_sum_k<<<512, 256, 0, stream>>>(X, csum);
    chunk_prefix_k<<<16, 256, 0, stream>>>(csum);
    write_mean_conv_k<<<512, 256, 0, stream>>>(X, csum, Acat);

    // --- main GEMMs ---
    mfma_ff1_k<<<dim3(8, 128), 256, 0, stream>>>(Acat, Bt1, bias2, Hbf);
    mfma_ff2_k<<<dim3(8, 128), 256, 0, stream>>>(Hbf, Bt2, ff2b, X, Pbf);

    // --- LayerNorm ---
    ln_k<<<BB * SS, 256, 0, stream>>>(Pbf, gam, bet, out);
}

// Round 4
// 366.774 us; speedup vs baseline: 5.1258x; 1.0805x over previous
//
#include <hip/hip_runtime.h>
#include <math.h>

#define BB 4
#define SS 4096
#define DD 1024
#define DVV 1024
#define CHUNK 128
#define NCHUNK (SS/CHUNK)   // 32

typedef unsigned short u16;
typedef __bf16 bf16x8 __attribute__((ext_vector_type(8)));
typedef float f32x4 __attribute__((ext_vector_type(4)));
#define AS1 __attribute__((address_space(1)))
#define AS3 __attribute__((address_space(3)))

__device__ __forceinline__ u16 f2bf(float f) {
    union { float f; unsigned u; } v; v.f = f;
    unsigned r = (v.u + 0x7fffu + ((v.u >> 16) & 1u)) >> 16;
    return (u16)r;
}
__device__ __forceinline__ float bf2f(u16 h) {
    union { unsigned u; float f; } v; v.u = ((unsigned)h) << 16;
    return v.f;
}

// ================= fused prep kernel =================
// sections (all independent):
//  [0,1024)    : values fp32 -> bf16 (Vbf)
//  [1024,2048) : transpose operator -> OpT
//  [2048,3072) : transpose ff1_bot  -> FbT
//  [3072,4096) : transpose ff1_top  -> Bt1[:,0:1024]
//  [4096,5120) : transpose ff2      -> Bt2
//  [5120,5632) : chunk_sum of X     -> csum
//  [5632,5664) : bias2 = vec @ ff1_bot + ff1_bias
__device__ __forceinline__ void transp_sec(const float* __restrict__ src, int src_ld,
                                           u16* __restrict__ dst, int dst_ld, int koff,
                                           int tb, float* sm) {
    int k0 = (tb & 31) * 32, n0 = (tb >> 5) * 32;
    int tx = threadIdx.x & 31, ty = threadIdx.x >> 5;
    #pragma unroll
    for (int i = 0; i < 32; i += 8)
        sm[(ty + i) * 33 + tx] = src[(size_t)(k0 + ty + i) * src_ld + n0 + tx];
    __syncthreads();
    #pragma unroll
    for (int i = 0; i < 32; i += 8)
        dst[(size_t)(n0 + ty + i) * dst_ld + koff + k0 + tx] = f2bf(sm[tx * 33 + ty + i]);
}

__global__ __launch_bounds__(256) void prep_k(const float* __restrict__ X,
                                              const float* __restrict__ vec,
                                              const float* __restrict__ values,
                                              const float* __restrict__ oper,
                                              const float* __restrict__ ff1,
                                              const float* __restrict__ ff1b,
                                              const float* __restrict__ ff2,
                                              u16* __restrict__ Vbf,
                                              u16* __restrict__ OpT,
                                              u16* __restrict__ FbT,
                                              u16* __restrict__ Bt1,
                                              u16* __restrict__ Bt2,
                                              float* __restrict__ csum,
                                              float* __restrict__ bias2) {
    __shared__ float sm[1056];   // 32*33 transpose tile / bias2 reduction
    int bid = blockIdx.x;
    int t = threadIdx.x;
    if (bid < 1024) {
        int g = bid * 256 + t;
        float4 v = *(const float4*)&values[(size_t)g * 4];
        u16* o = Vbf + (size_t)g * 4;
        o[0] = f2bf(v.x); o[1] = f2bf(v.y); o[2] = f2bf(v.z); o[3] = f2bf(v.w);
    } else if (bid < 2048) {
        transp_sec(oper, DD, OpT, 1024, 0, bid - 1024, sm);
    } else if (bid < 3072) {
        transp_sec(ff1 + (size_t)DD * DD, DD, FbT, 1024, 0, bid - 2048, sm);
    } else if (bid < 4096) {
        transp_sec(ff1, DD, Bt1, 2048, 0, bid - 3072, sm);
    } else if (bid < 5120) {
        transp_sec(ff2, DD, Bt2, 1024, 0, bid - 4096, sm);
    } else if (bid < 5632) {
        int g = (bid - 5120) * 256 + t;
        int d = g & (DD - 1);
        int c = (g >> 10) & (NCHUNK - 1);
        int b = g >> 15;
        const float* p = X + ((size_t)(b * SS + c * CHUNK)) * DD + d;
        float s = 0.f;
        for (int tt = 0; tt < CHUNK; ++tt) s += p[(size_t)tt * DD];
        csum[g] = s;
    } else {
        int j0 = (bid - 5632) * 32;
        int j = t & 31, g = t >> 5;
        const float* fb = ff1 + (size_t)DD * DD;
        float s[4] = {0.f, 0.f, 0.f, 0.f};
        for (int dv = g * 128; dv < g * 128 + 128; ++dv) {
            float w = fb[(size_t)dv * DD + j0 + j];
            s[0] += vec[dv] * w;
            s[1] += vec[DVV + dv] * w;
            s[2] += vec[2 * DVV + dv] * w;
            s[3] += vec[3 * DVV + dv] * w;
        }
        #pragma unroll
        for (int b = 0; b < 4; ++b) sm[g * 128 + b * 32 + j] = s[b];
        __syncthreads();
        if (t < 128) {
            int jj = t & 31, b = t >> 5;
            float acc = ff1b[j0 + jj];
            #pragma unroll
            for (int gg = 0; gg < 8; ++gg) acc += sm[gg * 128 + b * 32 + jj];
            bias2[b * DD + j0 + jj] = acc;
        }
    }
}

// in-place exclusive prefix over c of csum (b,c,d)
__global__ void chunk_prefix_k(float* csum) {
    int g = blockIdx.x * 256 + threadIdx.x;
    int d = g & (DD - 1);
    int b = g >> 10;
    float* p = csum + ((size_t)b * NCHUNK) * DD + d;
    float run = 0.f;
    for (int c = 0; c < NCHUNK; ++c) {
        float v = p[(size_t)c * DD];
        p[(size_t)c * DD] = run;
        run += v;
    }
}

// Xbf[row,d]=bf16(X); Mbf[row,d]=bf16(prefix_mean); 2 cols/thread
__global__ void write_mean_conv_k(const float* __restrict__ X, const float* __restrict__ csum,
                                  u16* __restrict__ Xbf, u16* __restrict__ Mbf) {
    int g = blockIdx.x * 256 + threadIdx.x;   // 65536 total
    int d = (g & 511) * 2;
    int c = (g >> 9) & (NCHUNK - 1);
    int b = g >> 14;
    size_t cs = ((size_t)(b * NCHUNK + c)) * DD + d;
    float run0 = csum[cs], run1 = csum[cs + 1];
    size_t base = ((size_t)(b * SS + c * CHUNK)) * DD + d;
    const float* p = X + base;
    u16* qx = Xbf + base;
    u16* qm = Mbf + base;
    int s0 = c * CHUNK;
    for (int t = 0; t < CHUNK; ++t) {
        float2 x = *(const float2*)&p[(size_t)t * DD];
        run0 += x.x; run1 += x.y;
        float inv = 1.0f / (float)(s0 + t + 1);
        u16 h0 = f2bf(x.x), h1 = f2bf(x.y);
        u16 m0 = f2bf(run0 * inv), m1 = f2bf(run1 * inv);
        *(ushort2*)&qx[(size_t)t * DD] = make_ushort2(h0, h1);
        *(ushort2*)&qm[(size_t)t * DD] = make_ushort2(m0, m1);
    }
}

// ================= 64x64 bf16 MFMA GEMM (precomputes) =================
__global__ __launch_bounds__(256) void mfma64_k(const u16* __restrict__ Ag,
                                                const u16* __restrict__ Btg,
                                                u16* __restrict__ dst, int K,
                                                int dld, int koff) {
    __shared__ u16 Alds[64 * 32];
    __shared__ u16 Blds[64 * 32];
    f32x4 acc[2][2] = {};
    int bm = blockIdx.y * 64, bn = blockIdx.x * 64;
    const int tid = threadIdx.x;
    const int wave = tid >> 6, lane = tid & 63;
    const int wm = wave & 1, wn = wave >> 1;
    const u16* ga = Ag + (size_t)(bm + (tid >> 2)) * K + (tid & 3) * 8;
    const u16* gb = Btg + (size_t)(bn + (tid >> 2)) * K + (tid & 3) * 8;
    const int lo = tid * 8;
    const int fk = (lane >> 4) * 8;
    for (int kt = 0; kt < K; kt += 32) {
        __builtin_amdgcn_global_load_lds((const AS1 void*)(ga + kt), (AS3 void*)(Alds + lo), 16, 0, 0);
        __builtin_amdgcn_global_load_lds((const AS1 void*)(gb + kt), (AS3 void*)(Blds + lo), 16, 0, 0);
        __syncthreads();
        bf16x8 af[2], bfr[2];
        #pragma unroll
        for (int i = 0; i < 2; ++i) af[i] = *(const bf16x8*)&Alds[(wm * 32 + i * 16 + (lane & 15)) * 32 + fk];
        #pragma unroll
        for (int i = 0; i < 2; ++i) bfr[i] = *(const bf16x8*)&Blds[(wn * 32 + i * 16 + (lane & 15)) * 32 + fk];
        #pragma unroll
        for (int mi = 0; mi < 2; ++mi)
            #pragma unroll
            for (int ni = 0; ni < 2; ++ni)
                acc[mi][ni] = __builtin_amdgcn_mfma_f32_16x16x32_bf16(af[mi], bfr[ni], acc[mi][ni], 0, 0, 0);
        __syncthreads();
    }
    #pragma unroll
    for (int mi = 0; mi < 2; ++mi)
        #pragma unroll
        for (int ni = 0; ni < 2; ++ni) {
            int col = bn + wn * 32 + ni * 16 + (lane & 15);
            #pragma unroll
            for (int r = 0; r < 4; ++r) {
                int row = bm + wm * 32 + mi * 16 + (lane >> 4) * 4 + r;
                dst[(size_t)row * dld + koff + col] = f2bf(acc[mi][ni][r]);
            }
        }
}

// ================= 128x128 bf16 MFMA GEMM core (m97 structure) =================
__device__ __forceinline__ void mfma_core(const u16* __restrict__ Ag, int lda,
                                          const u16* __restrict__ Btg, int ldb,
                                          int K, int bm, int bn,
                                          u16* Alds, u16* Blds, f32x4 acc[4][4]) {
    const int tid = threadIdx.x;
    const int wave = tid >> 6, lane = tid & 63;
    const int lrow = lane >> 2;
    const int lkb = (lane & 3) * 8;
    const int s0 = wave * 2;
    const u16* ga0 = Ag + (size_t)(bm + s0 * 16 + lrow) * lda + lkb;
    const u16* ga1 = Ag + (size_t)(bm + s0 * 16 + 16 + lrow) * lda + lkb;
    const u16* gb0 = Btg + (size_t)(bn + s0 * 16 + lrow) * ldb + lkb;
    const u16* gb1 = Btg + (size_t)(bn + s0 * 16 + 16 + lrow) * ldb + lkb;
    const int lo0 = s0 * 512;
    const int lo1 = lo0 + 512;
    const int fm = (wave & 1) * 64 + (lane & 15);
    const int fn = (wave >> 1) * 64 + (lane & 15);
    const int fk = (lane >> 4) * 8;
    for (int kt = 0; kt < K; kt += 32) {
        __builtin_amdgcn_global_load_lds((const AS1 void*)(ga0 + kt), (AS3 void*)(Alds + lo0), 16, 0, 0);
        __builtin_amdgcn_global_load_lds((const AS1 void*)(ga1 + kt), (AS3 void*)(Alds + lo1), 16, 0, 0);
        __builtin_amdgcn_global_load_lds((const AS1 void*)(gb0 + kt), (AS3 void*)(Blds + lo0), 16, 0, 0);
        __builtin_amdgcn_global_load_lds((const AS1 void*)(gb1 + kt), (AS3 void*)(Blds + lo1), 16, 0, 0);
        __syncthreads();
        bf16x8 af[4], bfr[4];
        #pragma unroll
        for (int i = 0; i < 4; ++i) af[i] = *(const bf16x8*)&Alds[(fm + i * 16) * 32 + fk];
        #pragma unroll
        for (int i = 0; i < 4; ++i) bfr[i] = *(const bf16x8*)&Blds[(fn + i * 16) * 32 + fk];
        #pragma unroll
        for (int mi = 0; mi < 4; ++mi)
            #pragma unroll
            for (int ni = 0; ni < 4; ++ni)
                acc[mi][ni] = __builtin_amdgcn_mfma_f32_16x16x32_bf16(af[mi], bfr[ni], acc[mi][ni], 0, 0, 0);
        __syncthreads();
    }
}

// XCD-aware remap: blocks sharing an A m-tile land on the same XCD (bid%8).
__device__ __forceinline__ void swizzle_mn(int nblk_n, int& bm, int& bn) {
    int bid = blockIdx.y * nblk_n + blockIdx.x;
    int x = bid & 7;
    int j = bid >> 3;
    int nt = j & (nblk_n - 1);
    int mt = (j >> 3) * 8 + x;
    bm = mt * 128;
    bn = nt * 128;
}

// hidden = relu(X@W1 + M@W2 + bias2[b]) -> bf16
__global__ __launch_bounds__(256) void mfma_ff1_k(const u16* __restrict__ Xbf,
                                                  const u16* __restrict__ Mbf,
                                                  const u16* __restrict__ Bt1,
                                                  const float* __restrict__ bias2,
                                                  u16* __restrict__ H) {
    __shared__ u16 Alds[128 * 32];
    __shared__ u16 Blds[128 * 32];
    f32x4 acc[4][4] = {};
    int bm, bn;
    swizzle_mn(8, bm, bn);
    mfma_core(Xbf, 1024, Bt1, 2048, 1024, bm, bn, Alds, Blds, acc);
    mfma_core(Mbf, 1024, Bt1 + 1024, 2048, 1024, bm, bn, Alds, Blds, acc);
    int wave = threadIdx.x >> 6, lane = threadIdx.x & 63;
    int rbase = bm + (wave & 1) * 64 + (lane >> 4) * 4;
    int cbase = bn + (wave >> 1) * 64 + (lane & 15);
    int bb = bm >> 12;
    #pragma unroll
    for (int mi = 0; mi < 4; ++mi)
        #pragma unroll
        for (int ni = 0; ni < 4; ++ni) {
            int col = cbase + ni * 16;
            float bz = bias2[bb * 1024 + col];
            #pragma unroll
            for (int r = 0; r < 4; ++r) {
                int row = rbase + mi * 16 + r;
                float v = acc[mi][ni][r] + bz;
                H[(size_t)row * 1024 + col] = f2bf(fmaxf(v, 0.f));
            }
        }
}

// P = H @ ff2 + ff2_bias + X -> bf16 (residual read from bf16 Xbf)
__global__ __launch_bounds__(256) void mfma_ff2_k(const u16* __restrict__ H,
                                                  const u16* __restrict__ Bt2,
                                                  const float* __restrict__ ff2b,
                                                  const u16* __restrict__ Xbf,
                                                  u16* __restrict__ P) {
    __shared__ u16 Alds[128 * 32];
    __shared__ u16 Blds[128 * 32];
    f32x4 acc[4][4] = {};
    int bm, bn;
    swizzle_mn(8, bm, bn);
    mfma_core(H, 1024, Bt2, 1024, 1024, bm, bn, Alds, Blds, acc);
    int wave = threadIdx.x >> 6, lane = threadIdx.x & 63;
    int rbase = bm + (wave & 1) * 64 + (lane >> 4) * 4;
    int cbase = bn + (wave >> 1) * 64 + (lane & 15);
    #pragma unroll
    for (int mi = 0; mi < 4; ++mi)
        #pragma unroll
        for (int ni = 0; ni < 4; ++ni) {
            int col = cbase + ni * 16;
            float bz = ff2b[col];
            #pragma unroll
            for (int r = 0; r < 4; ++r) {
                int row = rbase + mi * 16 + r;
                float xr = bf2f(Xbf[(size_t)row * 1024 + col]);
                P[(size_t)row * 1024 + col] = f2bf(acc[mi][ni][r] + bz + xr);
            }
        }
}

// ================= LayerNorm over bf16 P -> fp32 out =================
__global__ __launch_bounds__(256) void ln_k(const u16* __restrict__ P,
                                            const float* __restrict__ gam,
                                            const float* __restrict__ bet,
                                            float* __restrict__ out) {
    __shared__ float sbuf[4];
    int row = blockIdx.x;
    int tid = threadIdx.x;
    const u16* pr = P + (size_t)row * DD + tid * 4;
    float x0 = bf2f(pr[0]), x1 = bf2f(pr[1]), x2 = bf2f(pr[2]), x3 = bf2f(pr[3]);
    float local = x0 + x1 + x2 + x3;
    #pragma unroll
    for (int o = 32; o > 0; o >>= 1) local += __shfl_down(local, o, 64);
    if ((tid & 63) == 0) sbuf[tid >> 6] = local;
    __syncthreads();
    float mu = (sbuf[0] + sbuf[1] + sbuf[2] + sbuf[3]) * (1.0f / 1024.0f);
    __syncthreads();
    float d0 = x0 - mu, d1 = x1 - mu, d2 = x2 - mu, d3 = x3 - mu;
    float v2 = d0 * d0 + d1 * d1 + d2 * d2 + d3 * d3;
    #pragma unroll
    for (int o = 32; o > 0; o >>= 1) v2 += __shfl_down(v2, o, 64);
    if ((tid & 63) == 0) sbuf[tid >> 6] = v2;
    __syncthreads();
    float var = (sbuf[0] + sbuf[1] + sbuf[2] + sbuf[3]) * (1.0f / 1024.0f);
    float rs = rsqrtf(var + 1e-6f);
    float4 gg = *(const float4*)&gam[tid * 4];
    float4 bb = *(const float4*)&bet[tid * 4];
    float4 o4;
    o4.x = d0 * rs * gg.x + bb.x;
    o4.y = d1 * rs * gg.y + bb.y;
    o4.z = d2 * rs * gg.z + bb.z;
    o4.w = d3 * rs * gg.w + bb.w;
    *(float4*)&out[(size_t)row * DD + tid * 4] = o4;
}

extern "C" void kernel_launch(void* const* d_in, const int* in_sizes, int n_in,
                              void* d_out, int out_size, void* d_ws, size_t ws_size,
                              hipStream_t stream) {
    const float* X      = (const float*)d_in[0];
    const float* vec    = (const float*)d_in[1];
    // d_in[2] attention_weights, d_in[3] temperature: numerically dead (eps=1e-30 rounds away in fp32)
    const float* values = (const float*)d_in[4];
    const float* oper   = (const float*)d_in[5];
    const float* ff1    = (const float*)d_in[6];
    const float* ff1b   = (const float*)d_in[7];
    const float* ff2    = (const float*)d_in[8];
    const float* ff2b   = (const float*)d_in[9];
    const float* gam    = (const float*)d_in[10];
    const float* bet    = (const float*)d_in[11];
    float* out = (float*)d_out;

    char* w = (char*)d_ws;
    u16*   Xbf   = (u16*)w;                                  // 32 MB (16384x1024)
    u16*   Mbf   = (u16*)(w + (size_t)(32u << 20));          // 32 MB
    u16*   Pbf   = Mbf;                                      // alias: M dead after ff1
    u16*   Hbf   = (u16*)(w + (size_t)(64u << 20));          // 32 MB
    u16*   Vbf   = (u16*)(w + (size_t)(96u << 20));          // 2 MB values bf16
    u16*   OpT   = (u16*)(w + (size_t)(98u << 20));          // 2 MB operator^T bf16
    u16*   FbT   = (u16*)(w + (size_t)(100u << 20));         // 2 MB ff1_bot^T bf16
    u16*   WvBf  = (u16*)(w + (size_t)(102u << 20));         // 2 MB Wv bf16
    u16*   Bt1   = (u16*)(w + (size_t)(104u << 20));         // 4 MB (1024x2048)
    u16*   Bt2   = (u16*)(w + (size_t)(108u << 20));         // 2 MB (1024x1024)
    float* bias2 = (float*)(w + (size_t)(110u << 20));       // 16 KB
    float* csum  = (float*)(w + (size_t)(110u << 20) + (1u << 16)); // 512 KB

    // fused prep: converts, transposes, chunk_sum, bias2 (all independent)
    prep_k<<<5664, 256, 0, stream>>>(X, vec, values, oper, ff1, ff1b, ff2,
                                     Vbf, OpT, FbT, Bt1, Bt2, csum, bias2);

    // Wv(k,d) = sum_hk values(k,hk)*operT(d,hk); W2 into Bt1 high half
    mfma64_k<<<dim3(16, 16), 256, 0, stream>>>(Vbf, OpT, WvBf, 1024, 1024, 0);
    mfma64_k<<<dim3(16, 16), 256, 0, stream>>>(FbT, WvBf, Bt1, 1024, 2048, 1024);

    // prefix over chunks, then write Xbf/Mbf
    chunk_prefix_k<<<16, 256, 0, stream>>>(csum);
    write_mean_conv_k<<<256, 256, 0, stream>>>(X, csum, Xbf, Mbf);

    // main GEMMs
    mfma_ff1_k<<<dim3(8, 128), 256, 0, stream>>>(Xbf, Mbf, Bt1, bias2, Hbf);
    mfma_ff2_k<<<dim3(8, 128), 256, 0, stream>>>(Hbf, Bt2, ff2b, Xbf, Pbf);

    // LayerNorm
    ln_k<<<BB * SS, 256, 0, stream>>>(Pbf, gam, bet, out);
}

// Round 5
// 352.539 us; speedup vs baseline: 5.3328x; 1.0404x over previous
//
#include <hip/hip_runtime.h>
#include <math.h>

#define BB 4
#define SS 4096
#define DD 1024
#define DVV 1024
#define CHUNK 128
#define NCHUNK (SS/CHUNK)   // 32

typedef unsigned short u16;
typedef __bf16 bf16x8 __attribute__((ext_vector_type(8)));
typedef float f32x4 __attribute__((ext_vector_type(4)));
#define AS1 __attribute__((address_space(1)))
#define AS3 __attribute__((address_space(3)))

__device__ __forceinline__ u16 f2bf(float f) {
    union { float f; unsigned u; } v; v.f = f;
    unsigned r = (v.u + 0x7fffu + ((v.u >> 16) & 1u)) >> 16;
    return (u16)r;
}
__device__ __forceinline__ float bf2f(u16 h) {
    union { unsigned u; float f; } v; v.u = ((unsigned)h) << 16;
    return v.f;
}

// ================= fused prep kernel =================
//  [0,1024)    : values fp32 -> bf16 (Vbf)
//  [1024,2048) : transpose operator -> OpT
//  [2048,3072) : transpose ff1_bot  -> FbT
//  [3072,4096) : transpose ff1_top  -> Bt1[:,0:1024]
//  [4096,5120) : transpose ff2      -> Bt2
//  [5120,5632) : chunk_sum of X     -> csum
//  [5632,5664) : bias2 = vec @ ff1_bot + ff1_bias
__device__ __forceinline__ void transp_sec(const float* __restrict__ src, int src_ld,
                                           u16* __restrict__ dst, int dst_ld, int koff,
                                           int tb, float* sm) {
    int k0 = (tb & 31) * 32, n0 = (tb >> 5) * 32;
    int tx = threadIdx.x & 31, ty = threadIdx.x >> 5;
    #pragma unroll
    for (int i = 0; i < 32; i += 8)
        sm[(ty + i) * 33 + tx] = src[(size_t)(k0 + ty + i) * src_ld + n0 + tx];
    __syncthreads();
    #pragma unroll
    for (int i = 0; i < 32; i += 8)
        dst[(size_t)(n0 + ty + i) * dst_ld + koff + k0 + tx] = f2bf(sm[tx * 33 + ty + i]);
}

__global__ __launch_bounds__(256) void prep_k(const float* __restrict__ X,
                                              const float* __restrict__ vec,
                                              const float* __restrict__ values,
                                              const float* __restrict__ oper,
                                              const float* __restrict__ ff1,
                                              const float* __restrict__ ff1b,
                                              const float* __restrict__ ff2,
                                              u16* __restrict__ Vbf,
                                              u16* __restrict__ OpT,
                                              u16* __restrict__ FbT,
                                              u16* __restrict__ Bt1,
                                              u16* __restrict__ Bt2,
                                              float* __restrict__ csum,
                                              float* __restrict__ bias2) {
    __shared__ float sm[1056];
    int bid = blockIdx.x;
    int t = threadIdx.x;
    if (bid < 1024) {
        int g = bid * 256 + t;
        float4 v = *(const float4*)&values[(size_t)g * 4];
        u16* o = Vbf + (size_t)g * 4;
        o[0] = f2bf(v.x); o[1] = f2bf(v.y); o[2] = f2bf(v.z); o[3] = f2bf(v.w);
    } else if (bid < 2048) {
        transp_sec(oper, DD, OpT, 1024, 0, bid - 1024, sm);
    } else if (bid < 3072) {
        transp_sec(ff1 + (size_t)DD * DD, DD, FbT, 1024, 0, bid - 2048, sm);
    } else if (bid < 4096) {
        transp_sec(ff1, DD, Bt1, 2048, 0, bid - 3072, sm);
    } else if (bid < 5120) {
        transp_sec(ff2, DD, Bt2, 1024, 0, bid - 4096, sm);
    } else if (bid < 5632) {
        int g = (bid - 5120) * 256 + t;
        int d = g & (DD - 1);
        int c = (g >> 10) & (NCHUNK - 1);
        int b = g >> 15;
        const float* p = X + ((size_t)(b * SS + c * CHUNK)) * DD + d;
        float s = 0.f;
        for (int tt = 0; tt < CHUNK; ++tt) s += p[(size_t)tt * DD];
        csum[g] = s;
    } else {
        int j0 = (bid - 5632) * 32;
        int j = t & 31, g = t >> 5;
        const float* fb = ff1 + (size_t)DD * DD;
        float s[4] = {0.f, 0.f, 0.f, 0.f};
        for (int dv = g * 128; dv < g * 128 + 128; ++dv) {
            float w = fb[(size_t)dv * DD + j0 + j];
            s[0] += vec[dv] * w;
            s[1] += vec[DVV + dv] * w;
            s[2] += vec[2 * DVV + dv] * w;
            s[3] += vec[3 * DVV + dv] * w;
        }
        #pragma unroll
        for (int b = 0; b < 4; ++b) sm[g * 128 + b * 32 + j] = s[b];
        __syncthreads();
        if (t < 128) {
            int jj = t & 31, b = t >> 5;
            float acc = ff1b[j0 + jj];
            #pragma unroll
            for (int gg = 0; gg < 8; ++gg) acc += sm[gg * 128 + b * 32 + jj];
            bias2[b * DD + j0 + jj] = acc;
        }
    }
}

// ================= 64x64 bf16 MFMA GEMM (device fn, sectioned) =================
__device__ __forceinline__ void mfma64_dev(const u16* __restrict__ Ag,
                                           const u16* __restrict__ Btg,
                                           u16* __restrict__ dst, int K,
                                           int dld, int koff, int bm, int bn) {
    __shared__ u16 Alds[64 * 32];
    __shared__ u16 Blds[64 * 32];
    f32x4 acc[2][2] = {};
    const int tid = threadIdx.x;
    const int wave = tid >> 6, lane = tid & 63;
    const int wm = wave & 1, wn = wave >> 1;
    const u16* ga = Ag + (size_t)(bm + (tid >> 2)) * K + (tid & 3) * 8;
    const u16* gb = Btg + (size_t)(bn + (tid >> 2)) * K + (tid & 3) * 8;
    const int lo = tid * 8;
    const int fk = (lane >> 4) * 8;
    for (int kt = 0; kt < K; kt += 32) {
        __builtin_amdgcn_global_load_lds((const AS1 void*)(ga + kt), (AS3 void*)(Alds + lo), 16, 0, 0);
        __builtin_amdgcn_global_load_lds((const AS1 void*)(gb + kt), (AS3 void*)(Blds + lo), 16, 0, 0);
        __syncthreads();
        bf16x8 af[2], bfr[2];
        #pragma unroll
        for (int i = 0; i < 2; ++i) af[i] = *(const bf16x8*)&Alds[(wm * 32 + i * 16 + (lane & 15)) * 32 + fk];
        #pragma unroll
        for (int i = 0; i < 2; ++i) bfr[i] = *(const bf16x8*)&Blds[(wn * 32 + i * 16 + (lane & 15)) * 32 + fk];
        #pragma unroll
        for (int mi = 0; mi < 2; ++mi)
            #pragma unroll
            for (int ni = 0; ni < 2; ++ni)
                acc[mi][ni] = __builtin_amdgcn_mfma_f32_16x16x32_bf16(af[mi], bfr[ni], acc[mi][ni], 0, 0, 0);
        __syncthreads();
    }
    #pragma unroll
    for (int mi = 0; mi < 2; ++mi)
        #pragma unroll
        for (int ni = 0; ni < 2; ++ni) {
            int col = bn + wn * 32 + ni * 16 + (lane & 15);
            #pragma unroll
            for (int r = 0; r < 4; ++r) {
                int row = bm + wm * 32 + mi * 16 + (lane >> 4) * 4 + r;
                dst[(size_t)row * dld + koff + col] = f2bf(acc[mi][ni][r]);
            }
        }
}

// k2: [0,16) exclusive chunk-prefix of csum ; [16,272) Wv = Vbf @ OpT^T
__global__ __launch_bounds__(256) void k2_k(float* __restrict__ csum,
                                            const u16* __restrict__ Vbf,
                                            const u16* __restrict__ OpT,
                                            u16* __restrict__ WvBf) {
    int bid = blockIdx.x;
    if (bid < 16) {
        int g = bid * 256 + threadIdx.x;
        int d = g & (DD - 1);
        int b = g >> 10;
        float* p = csum + ((size_t)b * NCHUNK) * DD + d;
        float run = 0.f;
        for (int c = 0; c < NCHUNK; ++c) {
            float v = p[(size_t)c * DD];
            p[(size_t)c * DD] = run;
            run += v;
        }
    } else {
        int t2 = bid - 16;
        mfma64_dev(Vbf, OpT, WvBf, 1024, 1024, 0, (t2 >> 4) * 64, (t2 & 15) * 64);
    }
}

// k3: [0,256) write Acat = [bf16(X) | bf16(prefix_mean)] ; [256,512) W2 -> Bt1 high half
__global__ __launch_bounds__(256) void k3_k(const float* __restrict__ X,
                                            const float* __restrict__ csum,
                                            u16* __restrict__ Acat,
                                            const u16* __restrict__ FbT,
                                            const u16* __restrict__ WvBf,
                                            u16* __restrict__ Bt1) {
    int bid = blockIdx.x;
    if (bid < 256) {
        int g = bid * 256 + threadIdx.x;   // 65536; 2 cols/thread
        int d = (g & 511) * 2;
        int c = (g >> 9) & (NCHUNK - 1);
        int b = g >> 14;
        size_t cs = ((size_t)(b * NCHUNK + c)) * DD + d;
        float run0 = csum[cs], run1 = csum[cs + 1];
        const float* p = X + ((size_t)(b * SS + c * CHUNK)) * DD + d;
        u16* q = Acat + ((size_t)(b * SS + c * CHUNK)) * 2048 + d;
        int s0 = c * CHUNK;
        for (int t = 0; t < CHUNK; ++t) {
            float2 x = *(const float2*)&p[(size_t)t * DD];
            run0 += x.x; run1 += x.y;
            float inv = 1.0f / (float)(s0 + t + 1);
            *(ushort2*)&q[(size_t)t * 2048] = make_ushort2(f2bf(x.x), f2bf(x.y));
            *(ushort2*)&q[(size_t)t * 2048 + 1024] = make_ushort2(f2bf(run0 * inv), f2bf(run1 * inv));
        }
    } else {
        int t2 = bid - 256;
        mfma64_dev(FbT, WvBf, Bt1, 1024, 2048, 1024, (t2 >> 4) * 64, (t2 & 15) * 64);
    }
}

// ================= 128x128 bf16 MFMA GEMM core (m97 structure) =================
__device__ __forceinline__ void mfma_core(const u16* __restrict__ Ag, int lda,
                                          const u16* __restrict__ Btg, int ldb,
                                          int K, int bm, int bn,
                                          u16* Alds, u16* Blds, f32x4 acc[4][4]) {
    const int tid = threadIdx.x;
    const int wave = tid >> 6, lane = tid & 63;
    const int lrow = lane >> 2;
    const int lkb = (lane & 3) * 8;
    const int s0 = wave * 2;
    const u16* ga0 = Ag + (size_t)(bm + s0 * 16 + lrow) * lda + lkb;
    const u16* ga1 = Ag + (size_t)(bm + s0 * 16 + 16 + lrow) * lda + lkb;
    const u16* gb0 = Btg + (size_t)(bn + s0 * 16 + lrow) * ldb + lkb;
    const u16* gb1 = Btg + (size_t)(bn + s0 * 16 + 16 + lrow) * ldb + lkb;
    const int lo0 = s0 * 512;
    const int lo1 = lo0 + 512;
    const int fm = (wave & 1) * 64 + (lane & 15);
    const int fn = (wave >> 1) * 64 + (lane & 15);
    const int fk = (lane >> 4) * 8;
    for (int kt = 0; kt < K; kt += 32) {
        __builtin_amdgcn_global_load_lds((const AS1 void*)(ga0 + kt), (AS3 void*)(Alds + lo0), 16, 0, 0);
        __builtin_amdgcn_global_load_lds((const AS1 void*)(ga1 + kt), (AS3 void*)(Alds + lo1), 16, 0, 0);
        __builtin_amdgcn_global_load_lds((const AS1 void*)(gb0 + kt), (AS3 void*)(Blds + lo0), 16, 0, 0);
        __builtin_amdgcn_global_load_lds((const AS1 void*)(gb1 + kt), (AS3 void*)(Blds + lo1), 16, 0, 0);
        __syncthreads();
        bf16x8 af[4], bfr[4];
        #pragma unroll
        for (int i = 0; i < 4; ++i) af[i] = *(const bf16x8*)&Alds[(fm + i * 16) * 32 + fk];
        #pragma unroll
        for (int i = 0; i < 4; ++i) bfr[i] = *(const bf16x8*)&Blds[(fn + i * 16) * 32 + fk];
        #pragma unroll
        for (int mi = 0; mi < 4; ++mi)
            #pragma unroll
            for (int ni = 0; ni < 4; ++ni)
                acc[mi][ni] = __builtin_amdgcn_mfma_f32_16x16x32_bf16(af[mi], bfr[ni], acc[mi][ni], 0, 0, 0);
        __syncthreads();
    }
}

// XCD-aware remap: blocks sharing an A m-tile land on the same XCD (bid%8).
__device__ __forceinline__ void swizzle_mn(int nblk_n, int& bm, int& bn) {
    int bid = blockIdx.y * nblk_n + blockIdx.x;
    int x = bid & 7;
    int j = bid >> 3;
    int nt = j & (nblk_n - 1);
    int mt = (j >> 3) * 8 + x;
    bm = mt * 128;
    bn = nt * 128;
}

// hidden = relu(Acat @ Bt1^T + bias2[b]) -> bf16  (single K=2048 loop — measured best)
__global__ __launch_bounds__(256) void mfma_ff1_k(const u16* __restrict__ Acat,
                                                  const u16* __restrict__ Bt1,
                                                  const float* __restrict__ bias2,
                                                  u16* __restrict__ H) {
    __shared__ u16 Alds[128 * 32];
    __shared__ u16 Blds[128 * 32];
    f32x4 acc[4][4] = {};
    int bm, bn;
    swizzle_mn(8, bm, bn);
    mfma_core(Acat, 2048, Bt1, 2048, 2048, bm, bn, Alds, Blds, acc);
    int wave = threadIdx.x >> 6, lane = threadIdx.x & 63;
    int rbase = bm + (wave & 1) * 64 + (lane >> 4) * 4;
    int cbase = bn + (wave >> 1) * 64 + (lane & 15);
    int bb = bm >> 12;
    #pragma unroll
    for (int mi = 0; mi < 4; ++mi)
        #pragma unroll
        for (int ni = 0; ni < 4; ++ni) {
            int col = cbase + ni * 16;
            float bz = bias2[bb * 1024 + col];
            #pragma unroll
            for (int r = 0; r < 4; ++r) {
                int row = rbase + mi * 16 + r;
                float v = acc[mi][ni][r] + bz;
                H[(size_t)row * 1024 + col] = f2bf(fmaxf(v, 0.f));
            }
        }
}

// P = H @ ff2 + ff2_bias + X(fp32) -> bf16 (P aliases Acat)
__global__ __launch_bounds__(256) void mfma_ff2_k(const u16* __restrict__ H,
                                                  const u16* __restrict__ Bt2,
                                                  const float* __restrict__ ff2b,
                                                  const float* __restrict__ X,
                                                  u16* __restrict__ P) {
    __shared__ u16 Alds[128 * 32];
    __shared__ u16 Blds[128 * 32];
    f32x4 acc[4][4] = {};
    int bm, bn;
    swizzle_mn(8, bm, bn);
    mfma_core(H, 1024, Bt2, 1024, 1024, bm, bn, Alds, Blds, acc);
    int wave = threadIdx.x >> 6, lane = threadIdx.x & 63;
    int rbase = bm + (wave & 1) * 64 + (lane >> 4) * 4;
    int cbase = bn + (wave >> 1) * 64 + (lane & 15);
    #pragma unroll
    for (int mi = 0; mi < 4; ++mi)
        #pragma unroll
        for (int ni = 0; ni < 4; ++ni) {
            int col = cbase + ni * 16;
            float bz = ff2b[col];
            #pragma unroll
            for (int r = 0; r < 4; ++r) {
                int row = rbase + mi * 16 + r;
                P[(size_t)row * 1024 + col] = f2bf(acc[mi][ni][r] + bz + X[(size_t)row * 1024 + col]);
            }
        }
}

// ================= LayerNorm over bf16 P -> fp32 out =================
__global__ __launch_bounds__(256) void ln_k(const u16* __restrict__ P,
                                            const float* __restrict__ gam,
                                            const float* __restrict__ bet,
                                            float* __restrict__ out) {
    __shared__ float sbuf[4];
    int row = blockIdx.x;
    int tid = threadIdx.x;
    const u16* pr = P + (size_t)row * DD + tid * 4;
    float x0 = bf2f(pr[0]), x1 = bf2f(pr[1]), x2 = bf2f(pr[2]), x3 = bf2f(pr[3]);
    float local = x0 + x1 + x2 + x3;
    #pragma unroll
    for (int o = 32; o > 0; o >>= 1) local += __shfl_down(local, o, 64);
    if ((tid & 63) == 0) sbuf[tid >> 6] = local;
    __syncthreads();
    float mu = (sbuf[0] + sbuf[1] + sbuf[2] + sbuf[3]) * (1.0f / 1024.0f);
    __syncthreads();
    float d0 = x0 - mu, d1 = x1 - mu, d2 = x2 - mu, d3 = x3 - mu;
    float v2 = d0 * d0 + d1 * d1 + d2 * d2 + d3 * d3;
    #pragma unroll
    for (int o = 32; o > 0; o >>= 1) v2 += __shfl_down(v2, o, 64);
    if ((tid & 63) == 0) sbuf[tid >> 6] = v2;
    __syncthreads();
    float var = (sbuf[0] + sbuf[1] + sbuf[2] + sbuf[3]) * (1.0f / 1024.0f);
    float rs = rsqrtf(var + 1e-6f);
    float4 gg = *(const float4*)&gam[tid * 4];
    float4 bb = *(const float4*)&bet[tid * 4];
    float4 o4;
    o4.x = d0 * rs * gg.x + bb.x;
    o4.y = d1 * rs * gg.y + bb.y;
    o4.z = d2 * rs * gg.z + bb.z;
    o4.w = d3 * rs * gg.w + bb.w;
    *(float4*)&out[(size_t)row * DD + tid * 4] = o4;
}

extern "C" void kernel_launch(void* const* d_in, const int* in_sizes, int n_in,
                              void* d_out, int out_size, void* d_ws, size_t ws_size,
                              hipStream_t stream) {
    const float* X      = (const float*)d_in[0];
    const float* vec    = (const float*)d_in[1];
    // d_in[2] attention_weights, d_in[3] temperature: numerically dead (eps=1e-30 rounds away in fp32)
    const float* values = (const float*)d_in[4];
    const float* oper   = (const float*)d_in[5];
    const float* ff1    = (const float*)d_in[6];
    const float* ff1b   = (const float*)d_in[7];
    const float* ff2    = (const float*)d_in[8];
    const float* ff2b   = (const float*)d_in[9];
    const float* gam    = (const float*)d_in[10];
    const float* bet    = (const float*)d_in[11];
    float* out = (float*)d_out;

    char* w = (char*)d_ws;
    u16*   Acat  = (u16*)w;                                  // 64 MB (16384x2048)
    u16*   Pbf   = (u16*)w;                                  // alias: Acat dead when P written
    u16*   Hbf   = (u16*)(w + (size_t)(64u << 20));          // 32 MB
    u16*   Vbf   = (u16*)(w + (size_t)(96u << 20));          // 2 MB
    u16*   OpT   = (u16*)(w + (size_t)(98u << 20));          // 2 MB
    u16*   FbT   = (u16*)(w + (size_t)(100u << 20));         // 2 MB
    u16*   WvBf  = (u16*)(w + (size_t)(102u << 20));         // 2 MB
    u16*   Bt1   = (u16*)(w + (size_t)(104u << 20));         // 4 MB (1024x2048)
    u16*   Bt2   = (u16*)(w + (size_t)(108u << 20));         // 2 MB
    float* bias2 = (float*)(w + (size_t)(110u << 20));       // 16 KB
    float* csum  = (float*)(w + (size_t)(110u << 20) + (1u << 16)); // 512 KB

    // 1) fused prep: converts, transposes, chunk_sum, bias2
    prep_k<<<5664, 256, 0, stream>>>(X, vec, values, oper, ff1, ff1b, ff2,
                                     Vbf, OpT, FbT, Bt1, Bt2, csum, bias2);
    // 2) chunk-prefix || Wv = values @ operator
    k2_k<<<272, 256, 0, stream>>>(csum, Vbf, OpT, WvBf);
    // 3) Acat pack || W2 -> Bt1 high half
    k3_k<<<512, 256, 0, stream>>>(X, csum, Acat, FbT, WvBf, Bt1);
    // 4) hidden = relu([X|M] @ [W1;W2]^T + bias2)
    mfma_ff1_k<<<dim3(8, 128), 256, 0, stream>>>(Acat, Bt1, bias2, Hbf);
    // 5) P = hidden @ ff2^T + ff2b + X
    mfma_ff2_k<<<dim3(8, 128), 256, 0, stream>>>(Hbf, Bt2, ff2b, X, Pbf);
    // 6) LayerNorm
    ln_k<<<BB * SS, 256, 0, stream>>>(Pbf, gam, bet, out);
}